// Round 8
// baseline (508.512 us; speedup 1.0000x reference)
//
#include <hip/hip_runtime.h>
#include <hip/hip_bf16.h>

#define BQ 2
#define TT 2048
#define DD 512
#define HH 8
#define LL 4
#define DFFN 2048
#define WWIN 256
#define DHD 64
#define MM (BQ*TT)   // 4096 token rows
#define NOUT (MM*DD)

typedef __attribute__((ext_vector_type(8))) short bf16x8;
typedef __attribute__((ext_vector_type(4))) float f32x4;

// ---------- helpers ----------
__device__ __forceinline__ void lds_load16(const void* g, void* l) {
  __builtin_amdgcn_global_load_lds((const __attribute__((address_space(1))) void*)g,
                                   (__attribute__((address_space(3))) void*)l,
                                   16, 0, 0);
}

// Bijective XCD-chunk swizzle (T1): contiguous tile range per XCD.
__device__ __forceinline__ void xcd_remap(int& bx, int& by) {
  const int nwg = gridDim.x * gridDim.y;
  if ((nwg & 7) == 0) {
    const int orig = blockIdx.x + gridDim.x * blockIdx.y;
    const int id = (orig & 7) * (nwg >> 3) + (orig >> 3);
    bx = id % gridDim.x;
    by = id / gridDim.x;
  } else {
    bx = blockIdx.x;
    by = blockIdx.y;
  }
}

// ---------- diagnostic fill ----------
__global__ __launch_bounds__(256) void fill_const(float* __restrict__ out, float C, int n) {
  int i = blockIdx.x * 256 + threadIdx.x;
  if (i < n) out[i] = C;
}

// ---------- legacy prep (fallback flow) ----------
__global__ __launch_bounds__(256) void prep(const float* __restrict__ tokens,
                                            float* __restrict__ x,
                                            const float* __restrict__ bq,
                                            const float* __restrict__ bk,
                                            const float* __restrict__ bv,
                                            float* __restrict__ bqkvc) {
  const int b = blockIdx.x;
  if (b < 8192) {
    int i = b * 256 + threadIdx.x;
    x[i] = tokens[i];
  } else {
    int idx = (b - 8192) * 256 + threadIdx.x;
    if (idx < LL * 1536) {
      int l = idx / 1536, n = idx % 1536;
      float v;
      if (n < 512)       v = bq[l * 512 + n];
      else if (n < 1024) v = bk[l * 512 + n - 512];
      else               v = bv[l * 512 + n - 1024];
      bqkvc[idx] = v;
    }
  }
}

// ---------- weight transpose + bias concat + token row-stats partials ----------
// grid (4102, 4): b<3072 transpose; 3072..3077 bias concat; >=3078 (l==0 only)
// token stats: per-64-col-slice partial {sum, sumsq} -> pq[slice][row][2].
__global__ __launch_bounds__(256) void transpose_all(const float* __restrict__ Wq,
                                                     const float* __restrict__ Wk,
                                                     const float* __restrict__ Wv,
                                                     const float* __restrict__ Wo,
                                                     const float* __restrict__ W1,
                                                     const float* __restrict__ W2,
                                                     __hip_bfloat16* __restrict__ wqkvT,
                                                     __hip_bfloat16* __restrict__ woT,
                                                     __hip_bfloat16* __restrict__ w1T,
                                                     __hip_bfloat16* __restrict__ w2T,
                                                     const float* __restrict__ bq,
                                                     const float* __restrict__ bk,
                                                     const float* __restrict__ bv,
                                                     float* __restrict__ bqkvc,
                                                     const float* __restrict__ tokens,
                                                     float* __restrict__ pq) {
  const int l = blockIdx.y;
  const int b = blockIdx.x;
  if (b >= 3078) {                       // token stats partials (layer-0 LN1)
    if (l != 0) return;
    const int wave = threadIdx.x >> 6, lane = threadIdx.x & 63;
    const int row = (b - 3078) * 4 + wave;
    const float* xr = tokens + (size_t)row * DD;
    float v[8];
#pragma unroll
    for (int i = 0; i < 8; ++i) v[i] = xr[lane + i * 64];
#pragma unroll
    for (int i = 0; i < 8; ++i) {        // slice i = cols [i*64,(i+1)*64)
      float s = v[i], q = v[i] * v[i];
#pragma unroll
      for (int off = 32; off; off >>= 1) { s += __shfl_xor(s, off); q += __shfl_xor(q, off); }
      if (lane == 0) {
        pq[((size_t)i * 4096 + row) * 2]     = s;
        pq[((size_t)i * 4096 + row) * 2 + 1] = q;
      }
    }
    return;
  }
  if (b >= 3072) {                       // qkv bias concat
    int n = (b - 3072) * 256 + threadIdx.x;
    if (n < 1536) {
      float v;
      if (n < 512)       v = bq[l * 512 + n];
      else if (n < 1024) v = bk[l * 512 + n - 512];
      else               v = bv[l * 512 + n - 1024];
      bqkvc[l * 1536 + n] = v;
    }
    return;
  }
  __shared__ float tile[32][33];
  const float* src;
  __hip_bfloat16* dst;
  int K, N, t;
  if (b < 768) {
    int which = b >> 8; t = b & 255;
    src = ((which == 0) ? Wq : (which == 1) ? Wk : Wv) + (size_t)l * 262144;
    dst = wqkvT + (size_t)l * 786432 + which * 262144;
    K = 512; N = 512;
  } else if (b < 1024) {
    t = b - 768;  src = Wo + (size_t)l * 262144;  dst = woT + (size_t)l * 262144;  K = 512; N = 512;
  } else if (b < 2048) {
    t = b - 1024; src = W1 + (size_t)l * 1048576; dst = w1T + (size_t)l * 1048576; K = 512; N = 2048;
  } else {
    t = b - 2048; src = W2 + (size_t)l * 1048576; dst = w2T + (size_t)l * 1048576; K = 2048; N = 512;
  }
  const int tilesN = N >> 5;
  const int n0 = (t % tilesN) * 32, k0 = (t / tilesN) * 32;
  const int tx = threadIdx.x & 31, ty = threadIdx.x >> 5;
#pragma unroll
  for (int r = 0; r < 32; r += 8)
    tile[ty + r][tx] = src[(size_t)(k0 + ty + r) * N + n0 + tx];
  __syncthreads();
#pragma unroll
  for (int r = 0; r < 32; r += 8)
    dst[(size_t)(n0 + ty + r) * K + k0 + tx] = __float2bfloat16(tile[tx][ty + r]);
}

// ---------- LayerNorm kernels (fallback flow only) ----------
__global__ __launch_bounds__(256) void ln_kernel(const float* __restrict__ x,
                                                 const float* __restrict__ g,
                                                 const float* __restrict__ b,
                                                 __hip_bfloat16* __restrict__ out) {
  const int wave = threadIdx.x >> 6, lane = threadIdx.x & 63;
  const int row = blockIdx.x * 4 + wave;
  const float* xr = x + (size_t)row * DD;
  float v[8];
  float s = 0.f;
#pragma unroll
  for (int i = 0; i < 8; ++i) { v[i] = xr[lane + i * 64]; s += v[i]; }
#pragma unroll
  for (int off = 32; off; off >>= 1) s += __shfl_xor(s, off);
  float mu = s * (1.f / DD);
  float qs = 0.f;
#pragma unroll
  for (int i = 0; i < 8; ++i) { float d = v[i] - mu; qs += d * d; }
#pragma unroll
  for (int off = 32; off; off >>= 1) qs += __shfl_xor(qs, off);
  float rstd = rsqrtf(qs * (1.f / DD) + 1e-5f);
#pragma unroll
  for (int i = 0; i < 8; ++i) {
    int c = lane + i * 64;
    out[(size_t)row * DD + c] = __float2bfloat16((v[i] - mu) * rstd * g[c] + b[c]);
  }
}

__global__ __launch_bounds__(256) void ln_f32out(const float* __restrict__ x,
                                                 const float* __restrict__ g,
                                                 const float* __restrict__ b,
                                                 float* __restrict__ out) {
  const int wave = threadIdx.x >> 6, lane = threadIdx.x & 63;
  const int row = blockIdx.x * 4 + wave;
  const float* xr = x + (size_t)row * DD;
  float v[8];
  float s = 0.f;
#pragma unroll
  for (int i = 0; i < 8; ++i) { v[i] = xr[lane + i * 64]; s += v[i]; }
#pragma unroll
  for (int off = 32; off; off >>= 1) s += __shfl_xor(s, off);
  float mu = s * (1.f / DD);
  float qs = 0.f;
#pragma unroll
  for (int i = 0; i < 8; ++i) { float d = v[i] - mu; qs += d * d; }
#pragma unroll
  for (int off = 32; off; off >>= 1) qs += __shfl_xor(qs, off);
  float rstd = rsqrtf(qs * (1.f / DD) + 1e-5f);
#pragma unroll
  for (int i = 0; i < 8; ++i) {
    int c = lane + i * 64;
    out[(size_t)row * DD + c] = (v[i] - mu) * rstd * g[c] + b[c];
  }
}

// ---------- final LayerNorm from precomputed partials ----------
__global__ __launch_bounds__(256) void ln_f32out_stats(const float* __restrict__ x,
                                                       const float* __restrict__ ps,
                                                       const float* __restrict__ g,
                                                       const float* __restrict__ b,
                                                       float* __restrict__ out) {
  const int wave = threadIdx.x >> 6, lane = threadIdx.x & 63;
  const int row = blockIdx.x * 4 + wave;
  const int l8 = lane & 7;
  float s1 = ps[((size_t)l8 * 4096 + row) * 2];
  float s2 = ps[((size_t)l8 * 4096 + row) * 2 + 1];
#pragma unroll
  for (int off = 4; off; off >>= 1) { s1 += __shfl_xor(s1, off, 8); s2 += __shfl_xor(s2, off, 8); }
  const float mu = s1 * (1.f / DD);
  const float rstd = rsqrtf(s2 * (1.f / DD) - mu * mu + 1e-5f);
  const float* xr = x + (size_t)row * DD;
#pragma unroll
  for (int i = 0; i < 8; ++i) {
    int c = lane + i * 64;
    out[(size_t)row * DD + c] = (xr[c] - mu) * rstd * g[c] + b[c];
  }
}

// ---------- MFMA GEMM: double-pumped BK=64, XCD swizzle, LN-inline A, stats-out ----------
// LNA (BM==128 only): A comes from fp32 xsrc, normalized with stats from
// pstats[8][4096][2] and gamma/beta, reg-staged via ds_write_b128 into the
// SAME LDS layout as global_load_lds (dest elem = tid*8).
// PSTAT (EPI_RES, BM==BN==64): epilogue emits per-row {sum,sumsq} of x_new
// for this block's 64-col slice -> pout[bx][4096][2].
enum { EPI_BF16 = 0, EPI_GELU = 1, EPI_ADDF32 = 2, EPI_RES = 3 };

template <int EPI, bool ROPE, bool LNA, bool PSTAT, int BM, int BN>
__global__ __launch_bounds__(256, 1) void gemm_bt(const __hip_bfloat16* __restrict__ A,
                                                  const __hip_bfloat16* __restrict__ BT,
                                                  const float* __restrict__ bias,
                                                  __hip_bfloat16* __restrict__ Obf,
                                                  float* __restrict__ Of,
                                                  const float* __restrict__ Orin,
                                                  __hip_bfloat16* __restrict__ VTo,
                                                  const float* __restrict__ xsrc,
                                                  const float* __restrict__ pstats,
                                                  const float* __restrict__ gamma,
                                                  const float* __restrict__ beta,
                                                  float* __restrict__ pout,
                                                  int M, int N, int K, int KS,
                                                  int ostride, int ooff) {
  constexpr int MI = (BM == 64) ? 2 : ((BN == 128) ? 4 : 2);
  constexpr int NJ = (BM == 64) ? 2 : 4;
  __shared__ __align__(16) __hip_bfloat16 Ash[2][2][BM * 32];
  __shared__ __align__(16) __hip_bfloat16 Bsh[2][2][BN * 32];
  __shared__ __hip_bfloat16 gS[LNA ? 512 : 1];
  __shared__ __hip_bfloat16 bS[LNA ? 512 : 1];
  __shared__ float muS[LNA ? BM : 1];
  __shared__ float rsS[LNA ? BM : 1];
  const int tid = threadIdx.x;
  const int wave = tid >> 6;
  const int lane = tid & 63;
  int bx, by;
  xcd_remap(bx, by);
  const int m0 = by * BM;
  const int n0 = bx * BN;
  const int kbase = blockIdx.z * KS;
  const int wm = (BM == 64) ? ((wave >> 1) * 32)
                            : ((BN == 128) ? ((wave >> 1) * 64) : (wave * 32));
  const int wn = (BM == 64) ? ((wave & 1) * 32)
                            : ((BN == 128) ? ((wave & 1) * 64) : 0);
  const int l15 = lane & 15;
  const int quad = lane >> 4;

  f32x4 acc[MI][NJ] = {};

  const int r0 = tid >> 2;
  const int o0 = (tid & 3) * 8;

  const __hip_bfloat16* Ap0 = LNA ? nullptr : A + (size_t)(m0 + r0) * K + kbase + o0;
  const __hip_bfloat16* Ap1 = LNA ? nullptr : Ap0 + (size_t)64 * K;
  const __hip_bfloat16* Bp0 = BT + (size_t)(n0 + r0) * K + kbase + o0;
  const __hip_bfloat16* Bp1 = Bp0 + (size_t)64 * K;

  if constexpr (LNA) {
    for (int c = tid; c < 512; c += 256) {
      gS[c] = __float2bfloat16(gamma[c]);
      bS[c] = __float2bfloat16(beta[c]);
    }
    if (tid < BM) {
      const int row = m0 + tid;
      float s1 = 0.f, s2 = 0.f;
#pragma unroll
      for (int s = 0; s < 8; ++s) {
        s1 += pstats[((size_t)s * 4096 + row) * 2];
        s2 += pstats[((size_t)s * 4096 + row) * 2 + 1];
      }
      const float mu = s1 * (1.f / 512.f);
      muS[tid] = mu;
      rsS[tid] = rsqrtf(s2 * (1.f / 512.f) - mu * mu + 1e-5f);
    }
    __syncthreads();
  }

  auto stageA_ln = [&](int buf, int sub, int half, int k) {
    const int row = r0 + half * 64;                      // local row
    const float* xp = xsrc + (size_t)(m0 + row) * 512 + k + o0;
    float4 xa = *(const float4*)xp;
    float4 xb = *(const float4*)(xp + 4);
    const float mu = muS[row], rs = rsS[row];
    const int c0 = k + o0;
    float xv[8] = {xa.x, xa.y, xa.z, xa.w, xb.x, xb.y, xb.z, xb.w};
    bf16x8 o;
#pragma unroll
    for (int e = 0; e < 8; ++e) {
      float gv = __bfloat162float(gS[c0 + e]);
      float bv = __bfloat162float(bS[c0 + e]);
      ((__hip_bfloat16*)&o)[e] = __float2bfloat16((xv[e] - mu) * rs * gv + bv);
    }
    *(bf16x8*)&Ash[buf][sub][half * 2048 + tid * 8] = o;  // matches gload layout
  };

  auto stage64 = [&](int buf, int k) {
    if constexpr (LNA) {                                  // BM==128 only
      stageA_ln(buf, 0, 0, k);      stageA_ln(buf, 0, 1, k);
      stageA_ln(buf, 1, 0, k + 32); stageA_ln(buf, 1, 1, k + 32);
    } else {
      lds_load16(Ap0 + k,      &Ash[buf][0][tid * 0 + wave * 512]);
      lds_load16(Ap0 + k + 32, &Ash[buf][1][wave * 512]);
      if constexpr (BM == 128) {
        lds_load16(Ap1 + k,      &Ash[buf][0][2048 + wave * 512]);
        lds_load16(Ap1 + k + 32, &Ash[buf][1][2048 + wave * 512]);
      }
    }
    lds_load16(Bp0 + k,      &Bsh[buf][0][wave * 512]);
    lds_load16(Bp0 + k + 32, &Bsh[buf][1][wave * 512]);
    if constexpr (BN == 128) {
      lds_load16(Bp1 + k,      &Bsh[buf][0][2048 + wave * 512]);
      lds_load16(Bp1 + k + 32, &Bsh[buf][1][2048 + wave * 512]);
    }
  };
  auto compute = [&](const __hip_bfloat16* As, const __hip_bfloat16* Bs) {
    bf16x8 af[MI], bfr[NJ];
#pragma unroll
    for (int i = 0; i < MI; ++i)
      af[i] = *(const bf16x8*)&As[(wm + i * 16 + l15) * 32 + quad * 8];
#pragma unroll
    for (int j = 0; j < NJ; ++j)
      bfr[j] = *(const bf16x8*)&Bs[(wn + j * 16 + l15) * 32 + quad * 8];
#pragma unroll
    for (int i = 0; i < MI; ++i)
#pragma unroll
      for (int j = 0; j < NJ; ++j)
        acc[i][j] = __builtin_amdgcn_mfma_f32_16x16x32_bf16(af[i], bfr[j], acc[i][j], 0, 0, 0);
  };
  auto compute64 = [&](int buf) {
    compute(Ash[buf][0], Bsh[buf][0]);
    compute(Ash[buf][1], Bsh[buf][1]);
  };

  stage64(0, 0);
  for (int k0 = 0; k0 < KS; k0 += 128) {       // KS % 128 == 0
    __syncthreads();
    if (k0 + 64 < KS) stage64(1, k0 + 64);
    compute64(0);
    __syncthreads();
    if (k0 + 128 < KS) stage64(0, k0 + 128);
    compute64(1);
  }

  if constexpr (ROPE) {
    if (n0 < 1024) {
#pragma unroll
      for (int j = 0; j < 2; ++j) {
        const int col = n0 + wn + j * 16 + l15;
        const float bv0 = bias[col], bv1 = bias[col + 32];
        const float freq = __powf(10000.f, -(float)(j * 16 + l15) * (1.f / 32.f));
#pragma unroll
        for (int i = 0; i < MI; ++i) {
          const int row = m0 + wm + i * 16 + quad * 4;
#pragma unroll
          for (int r = 0; r < 4; ++r) {
            const int t = (row + r) & 2047;
            float sn, cs;
            __sincosf((float)t * freq, &sn, &cs);
            const float a0 = acc[i][j][r] + bv0;
            const float a1 = acc[i][j + 2][r] + bv1;
            const size_t idx = (size_t)(row + r) * ostride + ooff + col;
            Obf[idx]      = __float2bfloat16(a0 * cs - a1 * sn);
            Obf[idx + 32] = __float2bfloat16(a1 * cs + a0 * sn);
          }
        }
      }
    } else {
#pragma unroll
      for (int j = 0; j < NJ; ++j) {
        const int col = n0 + wn + j * 16 + l15;
        const float bv = bias[col];
        const int d = col - 1024;
#pragma unroll
        for (int i = 0; i < MI; ++i) {
          const int row = m0 + wm + i * 16 + quad * 4;
#pragma unroll
          for (int r = 0; r < 4; ++r)
            VTo[(size_t)d * 4096 + row + r] = __float2bfloat16(acc[i][j][r] + bv);
        }
      }
    }
    return;
  }

  float st1[MI][4] = {}, st2[MI][4] = {};
#pragma unroll
  for (int j = 0; j < NJ; ++j) {
    const int col = n0 + wn + j * 16 + l15;
    const float bv = (EPI == EPI_RES || blockIdx.z == 0) ? bias[col] : 0.f;
#pragma unroll
    for (int i = 0; i < MI; ++i) {
      const int row = m0 + wm + i * 16 + quad * 4;
#pragma unroll
      for (int r = 0; r < 4; ++r) {
        float v = acc[i][j][r] + bv;
        size_t idx = (size_t)(row + r) * ostride + ooff + col;
        if (EPI == EPI_BF16) {
          Obf[idx] = __float2bfloat16(v);
        } else if (EPI == EPI_GELU) {
          float ge = 0.5f * v * (1.f + erff(v * 0.70710678118654752f));
          Obf[idx] = __float2bfloat16(ge);
        } else if (EPI == EPI_RES) {
          const float vf = Orin[idx] + v;
          Of[idx] = vf;
          if constexpr (PSTAT) { st1[i][r] += vf; st2[i][r] += vf * vf; }
        } else {
          atomicAdd(&Of[idx], v);
        }
      }
    }
  }

  if constexpr (PSTAT) {          // BM==BN==64: emit per-row 64-col partials
    float* sS1 = (float*)&Ash[0][0][0];
    float* sS2 = sS1 + 64;
    float red1[MI][4], red2[MI][4];
#pragma unroll
    for (int i = 0; i < MI; ++i)
#pragma unroll
      for (int r = 0; r < 4; ++r) {
        float a = st1[i][r], c = st2[i][r];
#pragma unroll
        for (int off = 8; off; off >>= 1) { a += __shfl_xor(a, off, 16); c += __shfl_xor(c, off, 16); }
        red1[i][r] = a; red2[i][r] = c;
      }
    __syncthreads();
    if (wn == 0 && l15 == 0) {
#pragma unroll
      for (int i = 0; i < MI; ++i)
#pragma unroll
        for (int r = 0; r < 4; ++r) {
          const int rl = wm + i * 16 + quad * 4 + r;
          sS1[rl] = red1[i][r]; sS2[rl] = red2[i][r];
        }
    }
    __syncthreads();
    if (wn == 32 && l15 == 0) {
#pragma unroll
      for (int i = 0; i < MI; ++i)
#pragma unroll
        for (int r = 0; r < 4; ++r) {
          const int rl = wm + i * 16 + quad * 4 + r;
          const size_t po = ((size_t)bx * 4096 + m0 + rl) * 2;
          pout[po]     = sS1[rl] + red1[i][r];
          pout[po + 1] = sS2[rl] + red2[i][r];
        }
    }
  }
}

// ---------- MFMA flash attention (unchanged; XCD-chunked, NO-MAX softmax) ----------
__global__ __launch_bounds__(256, 1) void attn_mfma(const __hip_bfloat16* __restrict__ qkv,
                                                    const __hip_bfloat16* __restrict__ VT,
                                                    __hip_bfloat16* __restrict__ ao) {
  constexpr int KPAD = 72;
  constexpr int PPAD = 40;
  __shared__ __align__(16) __hip_bfloat16 Ksh[320 * KPAD];
  __shared__ __align__(16) __hip_bfloat16 Psh[4 * 16 * PPAD];
  const int tid = threadIdx.x;
  const int wave = tid >> 6;
  const int lane = tid & 63;
  const int l15 = lane & 15;
  const int quad = lane >> 4;
  int bx, by;
  xcd_remap(bx, by);
  const int bh = by;
  const int b = bh >> 3, h = bh & 7;
  const int q0 = bx * 64;
  const int j0 = (q0 >= WWIN) ? (q0 - WWIN) : 0;
  const int nk = (q0 + 63) - j0 + 1;

  const size_t baseK = ((size_t)(b * TT + j0)) * 1536 + 512 + h * 64;
  for (int c = tid; c < nk * 8; c += 256) {
    int row = c >> 3, cc = (c & 7) * 8;
    *(uint4*)&Ksh[row * KPAD + cc] = *(const uint4*)&qkv[baseK + (size_t)row * 1536 + cc];
  }
  __syncthreads();

  const int qt0 = q0 + wave * 16;
  const size_t baseQ = ((size_t)(b * TT + qt0 + l15)) * 1536 + h * 64;
  const bf16x8 aq0 = *(const bf16x8*)&qkv[baseQ + quad * 8];
  const bf16x8 aq1 = *(const bf16x8*)&qkv[baseQ + 32 + quad * 8];

  const __hip_bfloat16* V0 = VT + (size_t)(h * 64 + l15) * 4096 + (size_t)b * 2048 + j0;

  f32x4 o0 = {}, o1 = {}, o2 = {}, o3 = {};
  float lsum[4] = {0.f, 0.f, 0.f, 0.f};

  const int klo = (qt0 > (WWIN - 1)) ? (qt0 - (WWIN - 1)) : 0;
  const int c_lo = (klo - j0) >> 5;
  const int c_hi = (qt0 + 15 - j0) >> 5;
  __hip_bfloat16* Pw = &Psh[wave * 16 * PPAD];

  for (int c = c_lo; c <= c_hi; ++c) {
    const int krel = c * 32;
    bf16x8 bk00 = *(const bf16x8*)&Ksh[(krel + l15) * KPAD + quad * 8];
    bf16x8 bk01 = *(const bf16x8*)&Ksh[(krel + l15) * KPAD + 32 + quad * 8];
    bf16x8 bk10 = *(const bf16x8*)&Ksh[(krel + 16 + l15) * KPAD + quad * 8];
    bf16x8 bk11 = *(const bf16x8*)&Ksh[(krel + 16 + l15) * KPAD + 32 + quad * 8];
    f32x4 z = {};
    f32x4 s0 = __builtin_amdgcn_mfma_f32_16x16x32_bf16(aq0, bk00, z, 0, 0, 0);
    s0 = __builtin_amdgcn_mfma_f32_16x16x32_bf16(aq1, bk01, s0, 0, 0, 0);
    f32x4 s1 = __builtin_amdgcn_mfma_f32_16x16x32_bf16(aq0, bk10, z, 0, 0, 0);
    s1 = __builtin_amdgcn_mfma_f32_16x16x32_bf16(aq1, bk11, s1, 0, 0, 0);

    const int jj0 = j0 + krel + l15;
    const int jj1 = jj0 + 16;
#pragma unroll
    for (int r = 0; r < 4; ++r) {
      const int qrow = qt0 + quad * 4 + r;
      const bool ok0 = (jj0 <= qrow) && ((qrow - jj0) < WWIN);
      const bool ok1 = (jj1 <= qrow) && ((qrow - jj1) < WWIN);
      const float p0 = ok0 ? __expf(s0[r] * 0.125f) : 0.f;
      const float p1 = ok1 ? __expf(s1[r] * 0.125f) : 0.f;
      lsum[r] += p0 + p1;
      const int qloc = quad * 4 + r;
      Pw[qloc * PPAD + l15]      = __float2bfloat16(p0);
      Pw[qloc * PPAD + 16 + l15] = __float2bfloat16(p1);
    }
    asm volatile("s_waitcnt lgkmcnt(0)" ::: "memory");
    __builtin_amdgcn_wave_barrier();
    const bf16x8 pa = *(const bf16x8*)&Pw[l15 * PPAD + quad * 8];

    const int kgl = krel + quad * 8;
#pragma unroll
    for (int t = 0; t < 4; ++t) {
      const bf16x8 bv = *(const bf16x8*)&V0[(size_t)t * 65536 + kgl];
      if (t == 0)      o0 = __builtin_amdgcn_mfma_f32_16x16x32_bf16(pa, bv, o0, 0, 0, 0);
      else if (t == 1) o1 = __builtin_amdgcn_mfma_f32_16x16x32_bf16(pa, bv, o1, 0, 0, 0);
      else if (t == 2) o2 = __builtin_amdgcn_mfma_f32_16x16x32_bf16(pa, bv, o2, 0, 0, 0);
      else             o3 = __builtin_amdgcn_mfma_f32_16x16x32_bf16(pa, bv, o3, 0, 0, 0);
    }
    __builtin_amdgcn_wave_barrier();
  }

#pragma unroll
  for (int r = 0; r < 4; ++r) {
#pragma unroll
    for (int off = 8; off; off >>= 1) lsum[r] += __shfl_xor(lsum[r], off, 16);
  }

#pragma unroll
  for (int r = 0; r < 4; ++r) {
    const float inv = 1.f / lsum[r];
    const size_t ob = ((size_t)(b * TT + qt0 + quad * 4 + r)) * DD + h * 64 + l15;
    ao[ob]      = __float2bfloat16(o0[r] * inv);
    ao[ob + 16] = __float2bfloat16(o1[r] * inv);
    ao[ob + 32] = __float2bfloat16(o2[r] * inv);
    ao[ob + 48] = __float2bfloat16(o3[r] * inv);
  }
}

// ---------- host launch ----------
extern "C" void kernel_launch(void* const* d_in, const int* in_sizes, int n_in,
                              void* d_out, int out_size, void* d_ws, size_t ws_size,
                              hipStream_t stream) {
  float* outF = (float*)d_out;   // fp32 output; doubles as residual x

  int code = 0;
  if (n_in != 19)                      code = 1;
  else if (in_sizes[0]  != 2097152)    code = 2;
  else if (in_sizes[1]  != 1048576)    code = 3;
  else if (in_sizes[9]  != 4194304)    code = 4;
  else if (in_sizes[17] != 512)        code = 5;
  if (code != 0 || ws_size < 27287552ull) {
    float C = code ? (150.f + 15.f * (float)code) : (1000.f + (float)(ws_size >> 20));
    fill_const<<<8192, 256, 0, stream>>>(outF, C, NOUT);
    return;
  }

  const float* tokens = (const float*)d_in[0];
  const float* Wq  = (const float*)d_in[1];
  const float* Wk  = (const float*)d_in[2];
  const float* Wv  = (const float*)d_in[3];
  const float* Wo  = (const float*)d_in[4];
  const float* bq  = (const float*)d_in[5];
  const float* bk  = (const float*)d_in[6];
  const float* bv  = (const float*)d_in[7];
  const float* bo  = (const float*)d_in[8];
  const float* W1  = (const float*)d_in[9];
  const float* b1  = (const float*)d_in[10];
  const float* W2  = (const float*)d_in[11];
  const float* b2  = (const float*)d_in[12];
  const float* g1  = (const float*)d_in[13];
  const float* be1 = (const float*)d_in[14];
  const float* g2  = (const float*)d_in[15];
  const float* be2 = (const float*)d_in[16];
  const float* gf  = (const float*)d_in[17];
  const float* bf  = (const float*)d_in[18];

  char* ws = (char*)d_ws;
  __hip_bfloat16* xnao  = (__hip_bfloat16*)(ws + 0);          //  4,194,304 (ao; xn in fallback)
  __hip_bfloat16* qkv   = (__hip_bfloat16*)(ws + 4194304);    // 12,582,912
  __hip_bfloat16* hbuf  = (__hip_bfloat16*)(ws + 4194304);    // 16,777,216 span
  __hip_bfloat16* VT    = (__hip_bfloat16*)(ws + 16777216);   //  4,194,304 (attn phase only)

  const bool big = ws_size >= 46686208ull;   // weights + bias + 2 stats buffers
  __hip_bfloat16 *wqkvT, *woT, *w1T, *w2T;
  float* bqkvc;
  float* pq = nullptr;   // LN1 stats partials [8][4096][2]
  float* pw = nullptr;   // LN2 stats partials
  if (big) {
    wqkvT = (__hip_bfloat16*)(ws + 20971520);
    woT   = (__hip_bfloat16*)(ws + 27262976);
    w1T   = (__hip_bfloat16*)(ws + 29360128);
    w2T   = (__hip_bfloat16*)(ws + 37748736);
    bqkvc = (float*)(ws + 46137344);         //  24,576
    pq    = (float*)(ws + 46161920);         // 262,144
    pw    = (float*)(ws + 46424064);         // 262,144 (end 46,686,208)
  } else {
    wqkvT = (__hip_bfloat16*)(ws + 20971520);
    woT   = (__hip_bfloat16*)(ws + 22544384);
    w1T   = (__hip_bfloat16*)(ws + 23068672);
    w2T   = (__hip_bfloat16*)(ws + 25165824);
    bqkvc = (float*)(ws + 27262976);
  }
  __hip_bfloat16* xn = xnao;
  __hip_bfloat16* ao = xnao;
  float* x = outF;

  if (big) {
    // ---- flow: transposes+bias+token-stats upfront; LN fused into GEMMs ----
    transpose_all<<<dim3(4102, 4), 256, 0, stream>>>(Wq, Wk, Wv, Wo, W1, W2,
                                                     wqkvT, woT, w1T, w2T,
                                                     bq, bk, bv, bqkvc, tokens, pq);
    for (int l = 0; l < LL; ++l) {
      __hip_bfloat16* qkvT_l = wqkvT + (size_t)l * 786432;
      __hip_bfloat16* woT_l  = woT   + (size_t)l * 262144;
      __hip_bfloat16* w1T_l  = w1T   + (size_t)l * 1048576;
      __hip_bfloat16* w2T_l  = w2T   + (size_t)l * 1048576;
      const float* xsrc = (l == 0) ? tokens : x;

      // QKV: LN1-inline A + RoPE + VT   (128x64, grid 24x32)
      gemm_bt<EPI_BF16, true, true, false, 128, 64><<<dim3(24, 32), 256, 0, stream>>>(
          nullptr, qkvT_l, bqkvc + l * 1536, qkv, nullptr, nullptr, VT,
          xsrc, pq, g1 + l * 512, be1 + l * 512, nullptr,
          MM, 1536, 512, 512, 1536, 0);
      attn_mfma<<<dim3(32, 16), 256, 0, stream>>>(qkv, VT, ao);
      // Wo: fused residual + LN2 stats partials -> pw  (64x64, grid 8x64)
      gemm_bt<EPI_RES, false, false, true, 64, 64><<<dim3(8, 64), 256, 0, stream>>>(
          ao, woT_l, bo + l * 512, nullptr, x, xsrc, nullptr,
          nullptr, nullptr, nullptr, nullptr, pw,
          MM, 512, 512, 512, 512, 0);
      // FFN1: LN2-inline A + GELU   (128x128, grid 16x32)
      gemm_bt<EPI_GELU, false, true, false, 128, 128><<<dim3(16, 32), 256, 0, stream>>>(
          nullptr, w1T_l, b1 + l * 2048, hbuf, nullptr, nullptr, nullptr,
          x, pw, g2 + l * 512, be2 + l * 512, nullptr,
          MM, 2048, 512, 512, 2048, 0);
      // FFN2: fused residual + LN1 stats partials -> pq  (64x64, K=2048)
      gemm_bt<EPI_RES, false, false, true, 64, 64><<<dim3(8, 64), 256, 0, stream>>>(
          hbuf, w2T_l, b2 + l * 512, nullptr, x, x, nullptr,
          nullptr, nullptr, nullptr, nullptr, pq,
          MM, 512, 2048, 2048, 512, 0);
    }
    ln_f32out_stats<<<1024, 256, 0, stream>>>(x, pq, gf, bf, outF);
    return;
  }

  // ---- fallback: per-layer transposes, separate LN, atomic split-K ----
  prep<<<8216, 256, 0, stream>>>(tokens, x, bq, bk, bv, bqkvc);

  for (int l = 0; l < LL; ++l) {
    transpose_all<<<dim3(3072, 1), 256, 0, stream>>>(
        Wq + (size_t)l * 262144, Wk + (size_t)l * 262144, Wv + (size_t)l * 262144,
        Wo + (size_t)l * 262144, W1 + (size_t)l * 1048576, W2 + (size_t)l * 1048576,
        wqkvT, woT, w1T, w2T, bq, bk, bv, bqkvc, nullptr, nullptr);

    ln_kernel<<<1024, 256, 0, stream>>>(x, g1 + l * 512, be1 + l * 512, xn);
    gemm_bt<EPI_BF16, true, false, false, 128, 64><<<dim3(24, 32), 256, 0, stream>>>(
        xn, wqkvT, bqkvc + l * 1536, qkv, nullptr, nullptr, VT,
        nullptr, nullptr, nullptr, nullptr, nullptr,
        MM, 1536, 512, 512, 1536, 0);
    attn_mfma<<<dim3(32, 16), 256, 0, stream>>>(qkv, VT, ao);
    gemm_bt<EPI_ADDF32, false, false, false, 128, 64><<<dim3(8, 32, 2), 256, 0, stream>>>(
        ao, woT, bo + l * 512, nullptr, x, nullptr, nullptr,
        nullptr, nullptr, nullptr, nullptr, nullptr,
        MM, 512, 512, 256, 512, 0);
    ln_kernel<<<1024, 256, 0, stream>>>(x, g2 + l * 512, be2 + l * 512, xn);
    gemm_bt<EPI_GELU, false, false, false, 128, 128><<<dim3(16, 32), 256, 0, stream>>>(
        xn, w1T, b1 + l * 2048, hbuf, nullptr, nullptr, nullptr,
        nullptr, nullptr, nullptr, nullptr, nullptr,
        MM, 2048, 512, 512, 2048, 0);
    gemm_bt<EPI_ADDF32, false, false, false, 128, 128><<<dim3(4, 32, 4), 256, 0, stream>>>(
        hbuf, w2T, b2 + l * 512, nullptr, x, nullptr, nullptr,
        nullptr, nullptr, nullptr, nullptr, nullptr,
        MM, 512, 2048, 512, 512, 0);
  }
  ln_f32out<<<1024, 256, 0, stream>>>(x, gf, bf, outF);
}

// Round 9
// 504.255 us; speedup vs baseline: 1.0084x; 1.0084x over previous
//
#include <hip/hip_runtime.h>
#include <hip/hip_bf16.h>

#define BQ 2
#define TT 2048
#define DD 512
#define HH 8
#define LL 4
#define DFFN 2048
#define WWIN 256
#define DHD 64
#define MM (BQ*TT)   // 4096 token rows
#define NOUT (MM*DD)

typedef __attribute__((ext_vector_type(8))) short bf16x8;
typedef __attribute__((ext_vector_type(4))) float f32x4;

// ---------- helpers ----------
__device__ __forceinline__ void lds_load16(const void* g, void* l) {
  __builtin_amdgcn_global_load_lds((const __attribute__((address_space(1))) void*)g,
                                   (__attribute__((address_space(3))) void*)l,
                                   16, 0, 0);
}

// Bijective XCD-chunk swizzle (T1): contiguous tile range per XCD.
__device__ __forceinline__ void xcd_remap(int& bx, int& by) {
  const int nwg = gridDim.x * gridDim.y;
  if ((nwg & 7) == 0) {
    const int orig = blockIdx.x + gridDim.x * blockIdx.y;
    const int id = (orig & 7) * (nwg >> 3) + (orig >> 3);
    bx = id % gridDim.x;
    by = id / gridDim.x;
  } else {
    bx = blockIdx.x;
    by = blockIdx.y;
  }
}

// ---------- diagnostic fill ----------
__global__ __launch_bounds__(256) void fill_const(float* __restrict__ out, float C, int n) {
  int i = blockIdx.x * 256 + threadIdx.x;
  if (i < n) out[i] = C;
}

// ---------- legacy prep: tokens -> x copy + qkv bias concat (fallback flow) ----------
__global__ __launch_bounds__(256) void prep(const float* __restrict__ tokens,
                                            float* __restrict__ x,
                                            const float* __restrict__ bq,
                                            const float* __restrict__ bk,
                                            const float* __restrict__ bv,
                                            float* __restrict__ bqkvc) {
  const int b = blockIdx.x;
  if (b < 8192) {
    int i = b * 256 + threadIdx.x;
    x[i] = tokens[i];
  } else {
    int idx = (b - 8192) * 256 + threadIdx.x;
    if (idx < LL * 1536) {
      int l = idx / 1536, n = idx % 1536;
      float v;
      if (n < 512)       v = bq[l * 512 + n];
      else if (n < 1024) v = bk[l * 512 + n - 512];
      else               v = bv[l * 512 + n - 1024];
      bqkvc[idx] = v;
    }
  }
}

// ---------- weight transpose fp32(K,N)->bf16(N,K); + qkv bias concat blocks ----------
__global__ __launch_bounds__(256) void transpose_all(const float* __restrict__ Wq,
                                                     const float* __restrict__ Wk,
                                                     const float* __restrict__ Wv,
                                                     const float* __restrict__ Wo,
                                                     const float* __restrict__ W1,
                                                     const float* __restrict__ W2,
                                                     __hip_bfloat16* __restrict__ wqkvT,
                                                     __hip_bfloat16* __restrict__ woT,
                                                     __hip_bfloat16* __restrict__ w1T,
                                                     __hip_bfloat16* __restrict__ w2T,
                                                     const float* __restrict__ bq,
                                                     const float* __restrict__ bk,
                                                     const float* __restrict__ bv,
                                                     float* __restrict__ bqkvc) {
  const int l = blockIdx.y;
  const int b = blockIdx.x;
  if (b >= 3072) {
    int n = (b - 3072) * 256 + threadIdx.x;
    if (n < 1536) {
      float v;
      if (n < 512)       v = bq[l * 512 + n];
      else if (n < 1024) v = bk[l * 512 + n - 512];
      else               v = bv[l * 512 + n - 1024];
      bqkvc[l * 1536 + n] = v;
    }
    return;
  }
  __shared__ float tile[32][33];
  const float* src;
  __hip_bfloat16* dst;
  int K, N, t;
  if (b < 768) {
    int which = b >> 8; t = b & 255;
    src = ((which == 0) ? Wq : (which == 1) ? Wk : Wv) + (size_t)l * 262144;
    dst = wqkvT + (size_t)l * 786432 + which * 262144;
    K = 512; N = 512;
  } else if (b < 1024) {
    t = b - 768;  src = Wo + (size_t)l * 262144;  dst = woT + (size_t)l * 262144;  K = 512; N = 512;
  } else if (b < 2048) {
    t = b - 1024; src = W1 + (size_t)l * 1048576; dst = w1T + (size_t)l * 1048576; K = 512; N = 2048;
  } else {
    t = b - 2048; src = W2 + (size_t)l * 1048576; dst = w2T + (size_t)l * 1048576; K = 2048; N = 512;
  }
  const int tilesN = N >> 5;
  const int n0 = (t % tilesN) * 32, k0 = (t / tilesN) * 32;
  const int tx = threadIdx.x & 31, ty = threadIdx.x >> 5;
#pragma unroll
  for (int r = 0; r < 32; r += 8)
    tile[ty + r][tx] = src[(size_t)(k0 + ty + r) * N + n0 + tx];
  __syncthreads();
#pragma unroll
  for (int r = 0; r < 32; r += 8)
    dst[(size_t)(n0 + ty + r) * K + k0 + tx] = __float2bfloat16(tile[tx][ty + r]);
}

// ---------- LayerNorm: fp32 -> bf16 ----------
__global__ __launch_bounds__(256) void ln_kernel(const float* __restrict__ x,
                                                 const float* __restrict__ g,
                                                 const float* __restrict__ b,
                                                 __hip_bfloat16* __restrict__ out) {
  const int wave = threadIdx.x >> 6, lane = threadIdx.x & 63;
  const int row = blockIdx.x * 4 + wave;
  const float* xr = x + (size_t)row * DD;
  float v[8];
  float s = 0.f;
#pragma unroll
  for (int i = 0; i < 8; ++i) { v[i] = xr[lane + i * 64]; s += v[i]; }
#pragma unroll
  for (int off = 32; off; off >>= 1) s += __shfl_xor(s, off);
  float mu = s * (1.f / DD);
  float qs = 0.f;
#pragma unroll
  for (int i = 0; i < 8; ++i) { float d = v[i] - mu; qs += d * d; }
#pragma unroll
  for (int off = 32; off; off >>= 1) qs += __shfl_xor(qs, off);
  float rstd = rsqrtf(qs * (1.f / DD) + 1e-5f);
#pragma unroll
  for (int i = 0; i < 8; ++i) {
    int c = lane + i * 64;
    out[(size_t)row * DD + c] = __float2bfloat16((v[i] - mu) * rstd * g[c] + b[c]);
  }
}

// ---------- final LayerNorm: fp32 -> fp32 ----------
__global__ __launch_bounds__(256) void ln_f32out(const float* __restrict__ x,
                                                 const float* __restrict__ g,
                                                 const float* __restrict__ b,
                                                 float* __restrict__ out) {
  const int wave = threadIdx.x >> 6, lane = threadIdx.x & 63;
  const int row = blockIdx.x * 4 + wave;
  const float* xr = x + (size_t)row * DD;
  float v[8];
  float s = 0.f;
#pragma unroll
  for (int i = 0; i < 8; ++i) { v[i] = xr[lane + i * 64]; s += v[i]; }
#pragma unroll
  for (int off = 32; off; off >>= 1) s += __shfl_xor(s, off);
  float mu = s * (1.f / DD);
  float qs = 0.f;
#pragma unroll
  for (int i = 0; i < 8; ++i) { float d = v[i] - mu; qs += d * d; }
#pragma unroll
  for (int off = 32; off; off >>= 1) qs += __shfl_xor(qs, off);
  float rstd = rsqrtf(qs * (1.f / DD) + 1e-5f);
#pragma unroll
  for (int i = 0; i < 8; ++i) {
    int c = lane + i * 64;
    out[(size_t)row * DD + c] = (v[i] - mu) * rstd * g[c] + b[c];
  }
}

// ---------- MFMA GEMM: double-pumped BK=64, XCD-chunk swizzled (R7-proven) ----------
enum { EPI_BF16 = 0, EPI_GELU = 1, EPI_ADDF32 = 2, EPI_RES = 3 };

template <int EPI, bool ROPE, int BM, int BN>
__global__ __launch_bounds__(256, 1) void gemm_bt(const __hip_bfloat16* __restrict__ A,
                                                  const __hip_bfloat16* __restrict__ BT,
                                                  const float* __restrict__ bias,
                                                  __hip_bfloat16* __restrict__ Obf,
                                                  float* __restrict__ Of,
                                                  const float* __restrict__ Orin,
                                                  __hip_bfloat16* __restrict__ VTo,
                                                  int M, int N, int K, int KS,
                                                  int ostride, int ooff) {
  constexpr int MI = (BM == 64) ? 2 : ((BN == 128) ? 4 : 2);
  constexpr int NJ = (BM == 64) ? 2 : 4;
  __shared__ __align__(16) __hip_bfloat16 Ash[2][2][BM * 32];
  __shared__ __align__(16) __hip_bfloat16 Bsh[2][2][BN * 32];
  const int tid = threadIdx.x;
  const int wave = tid >> 6;
  const int lane = tid & 63;
  int bx, by;
  xcd_remap(bx, by);
  const int m0 = by * BM;
  const int n0 = bx * BN;
  const int kbase = blockIdx.z * KS;
  const int wm = (BM == 64) ? ((wave >> 1) * 32)
                            : ((BN == 128) ? ((wave >> 1) * 64) : (wave * 32));
  const int wn = (BM == 64) ? ((wave & 1) * 32)
                            : ((BN == 128) ? ((wave & 1) * 64) : 0);
  const int l15 = lane & 15;
  const int quad = lane >> 4;

  f32x4 acc[MI][NJ] = {};

  const int r0 = tid >> 2;
  const int o0 = (tid & 3) * 8;

  const __hip_bfloat16* Ap0 = A + (size_t)(m0 + r0) * K + kbase + o0;
  const __hip_bfloat16* Ap1 = Ap0 + (size_t)64 * K;
  const __hip_bfloat16* Bp0 = BT + (size_t)(n0 + r0) * K + kbase + o0;
  const __hip_bfloat16* Bp1 = Bp0 + (size_t)64 * K;

  auto stage64 = [&](int buf, int k) {
    lds_load16(Ap0 + k,      &Ash[buf][0][wave * 512]);
    lds_load16(Ap0 + k + 32, &Ash[buf][1][wave * 512]);
    if constexpr (BM == 128) {
      lds_load16(Ap1 + k,      &Ash[buf][0][2048 + wave * 512]);
      lds_load16(Ap1 + k + 32, &Ash[buf][1][2048 + wave * 512]);
    }
    lds_load16(Bp0 + k,      &Bsh[buf][0][wave * 512]);
    lds_load16(Bp0 + k + 32, &Bsh[buf][1][wave * 512]);
    if constexpr (BN == 128) {
      lds_load16(Bp1 + k,      &Bsh[buf][0][2048 + wave * 512]);
      lds_load16(Bp1 + k + 32, &Bsh[buf][1][2048 + wave * 512]);
    }
  };
  auto compute = [&](const __hip_bfloat16* As, const __hip_bfloat16* Bs) {
    bf16x8 af[MI], bfr[NJ];
#pragma unroll
    for (int i = 0; i < MI; ++i)
      af[i] = *(const bf16x8*)&As[(wm + i * 16 + l15) * 32 + quad * 8];
#pragma unroll
    for (int j = 0; j < NJ; ++j)
      bfr[j] = *(const bf16x8*)&Bs[(wn + j * 16 + l15) * 32 + quad * 8];
#pragma unroll
    for (int i = 0; i < MI; ++i)
#pragma unroll
      for (int j = 0; j < NJ; ++j)
        acc[i][j] = __builtin_amdgcn_mfma_f32_16x16x32_bf16(af[i], bfr[j], acc[i][j], 0, 0, 0);
  };
  auto compute64 = [&](int buf) {
    compute(Ash[buf][0], Bsh[buf][0]);
    compute(Ash[buf][1], Bsh[buf][1]);
  };

  stage64(0, 0);
  for (int k0 = 0; k0 < KS; k0 += 128) {       // KS % 128 == 0
    __syncthreads();
    if (k0 + 64 < KS) stage64(1, k0 + 64);
    compute64(0);
    __syncthreads();
    if (k0 + 128 < KS) stage64(0, k0 + 128);
    compute64(1);
  }

  if constexpr (ROPE) {
    if (n0 < 1024) {
      // q/k sections: rotate (d, d+32) pairs; write to qkv row-major
#pragma unroll
      for (int j = 0; j < 2; ++j) {
        const int col = n0 + wn + j * 16 + l15;
        const float bv0 = bias[col], bv1 = bias[col + 32];
        const float freq = __powf(10000.f, -(float)(j * 16 + l15) * (1.f / 32.f));
#pragma unroll
        for (int i = 0; i < MI; ++i) {
          const int row = m0 + wm + i * 16 + quad * 4;
#pragma unroll
          for (int r = 0; r < 4; ++r) {
            const int t = (row + r) & 2047;
            float sn, cs;
            __sincosf((float)t * freq, &sn, &cs);
            const float a0 = acc[i][j][r] + bv0;
            const float a1 = acc[i][j + 2][r] + bv1;
            const size_t idx = (size_t)(row + r) * ostride + ooff + col;
            Obf[idx]      = __float2bfloat16(a0 * cs - a1 * sn);
            Obf[idx + 32] = __float2bfloat16(a1 * cs + a0 * sn);
          }
        }
      }
    } else {
      // V section: bias + store transposed VT[d][token]
#pragma unroll
      for (int j = 0; j < NJ; ++j) {
        const int col = n0 + wn + j * 16 + l15;
        const float bv = bias[col];
        const int d = col - 1024;
#pragma unroll
        for (int i = 0; i < MI; ++i) {
          const int row = m0 + wm + i * 16 + quad * 4;
#pragma unroll
          for (int r = 0; r < 4; ++r)
            VTo[(size_t)d * 4096 + row + r] = __float2bfloat16(acc[i][j][r] + bv);
        }
      }
    }
    return;
  }

#pragma unroll
  for (int j = 0; j < NJ; ++j) {
    const int col = n0 + wn + j * 16 + l15;
    const float bv = (EPI == EPI_RES || blockIdx.z == 0) ? bias[col] : 0.f;
#pragma unroll
    for (int i = 0; i < MI; ++i) {
      const int row = m0 + wm + i * 16 + quad * 4;
#pragma unroll
      for (int r = 0; r < 4; ++r) {
        float v = acc[i][j][r] + bv;
        size_t idx = (size_t)(row + r) * ostride + ooff + col;
        if (EPI == EPI_BF16) {
          Obf[idx] = __float2bfloat16(v);
        } else if (EPI == EPI_GELU) {
          float ge = 0.5f * v * (1.f + erff(v * 0.70710678118654752f));
          Obf[idx] = __float2bfloat16(ge);
        } else if (EPI == EPI_RES) {
          Of[idx] = Orin[idx] + v;               // fused residual, race-free
        } else {
          atomicAdd(&Of[idx], v);                // fallback split-K
        }
      }
    }
  }
}

// ---------- MFMA flash attention; NO K-staging (K L2-resident per XCD) ----------
// m169/Common-mistake #7: LDS-staging L2-fit data is pure overhead. K fragments
// read directly from qkv (16B-aligned vector loads, L2-hit); Ksh + staging loop
// + block barrier removed. OOB-masked rows land in the adjacent in-workspace VT
// region (no fault) and are zeroed by the ok0/ok1 masks, as before.
__global__ __launch_bounds__(256, 1) void attn_mfma(const __hip_bfloat16* __restrict__ qkv,
                                                    const __hip_bfloat16* __restrict__ VT,
                                                    __hip_bfloat16* __restrict__ ao) {
  constexpr int PPAD = 40;
  __shared__ __align__(16) __hip_bfloat16 Psh[4 * 16 * PPAD];
  const int tid = threadIdx.x;
  const int wave = tid >> 6;
  const int lane = tid & 63;
  const int l15 = lane & 15;
  const int quad = lane >> 4;
  int bx, by;
  xcd_remap(bx, by);                 // grid (32,16): 512 wg, %8==0
  const int bh = by;
  const int b = bh >> 3, h = bh & 7;
  const int q0 = bx * 64;
  const int j0 = (q0 >= WWIN) ? (q0 - WWIN) : 0;   // 64-aligned

  const __hip_bfloat16* Kbase = qkv + ((size_t)(b * TT + j0)) * 1536 + 512 + h * 64;

  const int qt0 = q0 + wave * 16;
  const size_t baseQ = ((size_t)(b * TT + qt0 + l15)) * 1536 + h * 64;
  const bf16x8 aq0 = *(const bf16x8*)&qkv[baseQ + quad * 8];
  const bf16x8 aq1 = *(const bf16x8*)&qkv[baseQ + 32 + quad * 8];

  const __hip_bfloat16* V0 = VT + (size_t)(h * 64 + l15) * 4096 + (size_t)b * 2048 + j0;

  f32x4 o0 = {}, o1 = {}, o2 = {}, o3 = {};
  float lsum[4] = {0.f, 0.f, 0.f, 0.f};

  const int klo = (qt0 > (WWIN - 1)) ? (qt0 - (WWIN - 1)) : 0;
  const int c_lo = (klo - j0) >> 5;
  const int c_hi = (qt0 + 15 - j0) >> 5;
  __hip_bfloat16* Pw = &Psh[wave * 16 * PPAD];

  for (int c = c_lo; c <= c_hi; ++c) {
    const int krel = c * 32;
    const size_t kr0 = (size_t)(krel + l15) * 1536;
    const size_t kr1 = (size_t)(krel + 16 + l15) * 1536;
    bf16x8 bk00 = *(const bf16x8*)&Kbase[kr0 + quad * 8];
    bf16x8 bk01 = *(const bf16x8*)&Kbase[kr0 + 32 + quad * 8];
    bf16x8 bk10 = *(const bf16x8*)&Kbase[kr1 + quad * 8];
    bf16x8 bk11 = *(const bf16x8*)&Kbase[kr1 + 32 + quad * 8];
    f32x4 z = {};
    f32x4 s0 = __builtin_amdgcn_mfma_f32_16x16x32_bf16(aq0, bk00, z, 0, 0, 0);
    s0 = __builtin_amdgcn_mfma_f32_16x16x32_bf16(aq1, bk01, s0, 0, 0, 0);
    f32x4 s1 = __builtin_amdgcn_mfma_f32_16x16x32_bf16(aq0, bk10, z, 0, 0, 0);
    s1 = __builtin_amdgcn_mfma_f32_16x16x32_bf16(aq1, bk11, s1, 0, 0, 0);

    const int jj0 = j0 + krel + l15;
    const int jj1 = jj0 + 16;
#pragma unroll
    for (int r = 0; r < 4; ++r) {
      const int qrow = qt0 + quad * 4 + r;
      const bool ok0 = (jj0 <= qrow) && ((qrow - jj0) < WWIN);
      const bool ok1 = (jj1 <= qrow) && ((qrow - jj1) < WWIN);
      const float p0 = ok0 ? __expf(s0[r] * 0.125f) : 0.f;
      const float p1 = ok1 ? __expf(s1[r] * 0.125f) : 0.f;
      lsum[r] += p0 + p1;
      const int qloc = quad * 4 + r;
      Pw[qloc * PPAD + l15]      = __float2bfloat16(p0);
      Pw[qloc * PPAD + 16 + l15] = __float2bfloat16(p1);
    }
    asm volatile("s_waitcnt lgkmcnt(0)" ::: "memory");
    __builtin_amdgcn_wave_barrier();
    const bf16x8 pa = *(const bf16x8*)&Pw[l15 * PPAD + quad * 8];

    const int kgl = krel + quad * 8;
#pragma unroll
    for (int t = 0; t < 4; ++t) {
      const bf16x8 bv = *(const bf16x8*)&V0[(size_t)t * 65536 + kgl];
      if (t == 0)      o0 = __builtin_amdgcn_mfma_f32_16x16x32_bf16(pa, bv, o0, 0, 0, 0);
      else if (t == 1) o1 = __builtin_amdgcn_mfma_f32_16x16x32_bf16(pa, bv, o1, 0, 0, 0);
      else if (t == 2) o2 = __builtin_amdgcn_mfma_f32_16x16x32_bf16(pa, bv, o2, 0, 0, 0);
      else             o3 = __builtin_amdgcn_mfma_f32_16x16x32_bf16(pa, bv, o3, 0, 0, 0);
    }
    __builtin_amdgcn_wave_barrier();
  }

#pragma unroll
  for (int r = 0; r < 4; ++r) {
#pragma unroll
    for (int off = 8; off; off >>= 1) lsum[r] += __shfl_xor(lsum[r], off, 16);
  }

#pragma unroll
  for (int r = 0; r < 4; ++r) {
    const float inv = 1.f / lsum[r];
    const size_t ob = ((size_t)(b * TT + qt0 + quad * 4 + r)) * DD + h * 64 + l15;
    ao[ob]      = __float2bfloat16(o0[r] * inv);
    ao[ob + 16] = __float2bfloat16(o1[r] * inv);
    ao[ob + 32] = __float2bfloat16(o2[r] * inv);
    ao[ob + 48] = __float2bfloat16(o3[r] * inv);
  }
}

// ---------- host launch ----------
extern "C" void kernel_launch(void* const* d_in, const int* in_sizes, int n_in,
                              void* d_out, int out_size, void* d_ws, size_t ws_size,
                              hipStream_t stream) {
  float* outF = (float*)d_out;   // fp32 output; doubles as residual x

  int code = 0;
  if (n_in != 19)                      code = 1;
  else if (in_sizes[0]  != 2097152)    code = 2;
  else if (in_sizes[1]  != 1048576)    code = 3;
  else if (in_sizes[9]  != 4194304)    code = 4;
  else if (in_sizes[17] != 512)        code = 5;
  if (code != 0 || ws_size < 27287552ull) {
    float C = code ? (150.f + 15.f * (float)code) : (1000.f + (float)(ws_size >> 20));
    fill_const<<<8192, 256, 0, stream>>>(outF, C, NOUT);
    return;
  }

  const float* tokens = (const float*)d_in[0];
  const float* Wq  = (const float*)d_in[1];
  const float* Wk  = (const float*)d_in[2];
  const float* Wv  = (const float*)d_in[3];
  const float* Wo  = (const float*)d_in[4];
  const float* bq  = (const float*)d_in[5];
  const float* bk  = (const float*)d_in[6];
  const float* bv  = (const float*)d_in[7];
  const float* bo  = (const float*)d_in[8];
  const float* W1  = (const float*)d_in[9];
  const float* b1  = (const float*)d_in[10];
  const float* W2  = (const float*)d_in[11];
  const float* b2  = (const float*)d_in[12];
  const float* g1  = (const float*)d_in[13];
  const float* be1 = (const float*)d_in[14];
  const float* g2  = (const float*)d_in[15];
  const float* be2 = (const float*)d_in[16];
  const float* gf  = (const float*)d_in[17];
  const float* bf  = (const float*)d_in[18];

  char* ws = (char*)d_ws;
  __hip_bfloat16* xnao  = (__hip_bfloat16*)(ws + 0);          //  4,194,304 (xn/ao aliased)
  __hip_bfloat16* qkv   = (__hip_bfloat16*)(ws + 4194304);    // 12,582,912
  __hip_bfloat16* hbuf  = (__hip_bfloat16*)(ws + 4194304);    // 16,777,216 span
  __hip_bfloat16* VT    = (__hip_bfloat16*)(ws + 16777216);   //  4,194,304 (attn phase only)

  const bool big = ws_size >= 46161920ull;   // hoisted transposed weights fit
  __hip_bfloat16 *wqkvT, *woT, *w1T, *w2T;
  float* bqkvc;
  if (big) {
    wqkvT = (__hip_bfloat16*)(ws + 20971520);
    woT   = (__hip_bfloat16*)(ws + 27262976);
    w1T   = (__hip_bfloat16*)(ws + 29360128);
    w2T   = (__hip_bfloat16*)(ws + 37748736);
    bqkvc = (float*)(ws + 46137344);
  } else {
    wqkvT = (__hip_bfloat16*)(ws + 20971520);
    woT   = (__hip_bfloat16*)(ws + 22544384);
    w1T   = (__hip_bfloat16*)(ws + 23068672);
    w2T   = (__hip_bfloat16*)(ws + 25165824);
    bqkvc = (float*)(ws + 27262976);
  }
  __hip_bfloat16* xn = xnao;
  __hip_bfloat16* ao = xnao;
  float* x = outF;

  if (big) {
    // ---- flow: hoisted transposes (+bias blocks), fused-residual GEMMs ----
    transpose_all<<<dim3(3078, 4), 256, 0, stream>>>(Wq, Wk, Wv, Wo, W1, W2,
                                                     wqkvT, woT, w1T, w2T,
                                                     bq, bk, bv, bqkvc);
    ln_kernel<<<1024, 256, 0, stream>>>(tokens, g1, be1, xn);
    for (int l = 0; l < LL; ++l) {
      __hip_bfloat16* qkvT_l = wqkvT + (size_t)l * 786432;
      __hip_bfloat16* woT_l  = woT   + (size_t)l * 262144;
      __hip_bfloat16* w1T_l  = w1T   + (size_t)l * 1048576;
      __hip_bfloat16* w2T_l  = w2T   + (size_t)l * 1048576;

      gemm_bt<EPI_BF16, true, 128, 64><<<dim3(24, 32), 256, 0, stream>>>(
          xn, qkvT_l, bqkvc + l * 1536, qkv, nullptr, nullptr, VT,
          MM, 1536, 512, 512, 1536, 0);
      attn_mfma<<<dim3(32, 16), 256, 0, stream>>>(qkv, VT, ao);
      // Wo: 64x64 tile, full-K, fused residual (x = xin + ao@WoT + bo)
      gemm_bt<EPI_RES, false, 64, 64><<<dim3(8, 64), 256, 0, stream>>>(
          ao, woT_l, bo + l * 512, nullptr, x, (l == 0) ? tokens : x, nullptr,
          MM, 512, 512, 512, 512, 0);
      ln_kernel<<<1024, 256, 0, stream>>>(x, g2 + l * 512, be2 + l * 512, xn);
      gemm_bt<EPI_GELU, false, 128, 128><<<dim3(16, 32), 256, 0, stream>>>(
          xn, w1T_l, b1 + l * 2048, hbuf, nullptr, nullptr, nullptr,
          MM, 2048, 512, 512, 2048, 0);
      // FFN2: 64x64 tile, full-K=2048, fused residual (x += h@W2T + b2)
      gemm_bt<EPI_RES, false, 64, 64><<<dim3(8, 64), 256, 0, stream>>>(
          hbuf, w2T_l, b2 + l * 512, nullptr, x, x, nullptr,
          MM, 512, 2048, 2048, 512, 0);
      if (l < LL - 1)
        ln_kernel<<<1024, 256, 0, stream>>>(x, g1 + (l + 1) * 512,
                                            be1 + (l + 1) * 512, xn);
      else
        ln_f32out<<<1024, 256, 0, stream>>>(x, gf, bf, outF);  // in-place safe
    }
    return;
  }

  // ---- fallback: per-layer transposes, atomic split-K ----
  prep<<<8216, 256, 0, stream>>>(tokens, x, bq, bk, bv, bqkvc);

  for (int l = 0; l < LL; ++l) {
    transpose_all<<<dim3(3072, 1), 256, 0, stream>>>(
        Wq + (size_t)l * 262144, Wk + (size_t)l * 262144, Wv + (size_t)l * 262144,
        Wo + (size_t)l * 262144, W1 + (size_t)l * 1048576, W2 + (size_t)l * 1048576,
        wqkvT, woT, w1T, w2T, bq, bk, bv, bqkvc);

    ln_kernel<<<1024, 256, 0, stream>>>(x, g1 + l * 512, be1 + l * 512, xn);
    gemm_bt<EPI_BF16, true, 128, 64><<<dim3(24, 32), 256, 0, stream>>>(
        xn, wqkvT, bqkvc + l * 1536, qkv, nullptr, nullptr, VT,
        MM, 1536, 512, 512, 1536, 0);
    attn_mfma<<<dim3(32, 16), 256, 0, stream>>>(qkv, VT, ao);
    gemm_bt<EPI_ADDF32, false, 128, 64><<<dim3(8, 32, 2), 256, 0, stream>>>(
        ao, woT, bo + l * 512, nullptr, x, nullptr, nullptr,
        MM, 512, 512, 256, 512, 0);
    ln_kernel<<<1024, 256, 0, stream>>>(x, g2 + l * 512, be2 + l * 512, xn);
    gemm_bt<EPI_GELU, false, 128, 128><<<dim3(16, 32), 256, 0, stream>>>(
        xn, w1T, b1 + l * 2048, hbuf, nullptr, nullptr, nullptr,
        MM, 2048, 512, 512, 2048, 0);
    gemm_bt<EPI_ADDF32, false, 128, 128><<<dim3(4, 32, 4), 256, 0, stream>>>(
        hbuf, w2T, b2 + l * 512, nullptr, x, nullptr, nullptr,
        MM, 512, 2048, 512, 512, 0);
  }
  ln_f32out<<<1024, 256, 0, stream>>>(x, gf, bf, outF);
}

// Round 10
// 487.756 us; speedup vs baseline: 1.0426x; 1.0338x over previous
//
#include <hip/hip_runtime.h>
#include <hip/hip_bf16.h>

#define BQ 2
#define TT 2048
#define DD 512
#define HH 8
#define LL 4
#define DFFN 2048
#define WWIN 256
#define DHD 64
#define MM (BQ*TT)   // 4096 token rows
#define NOUT (MM*DD)

typedef __attribute__((ext_vector_type(8))) short bf16x8;
typedef __attribute__((ext_vector_type(4))) float f32x4;

// ---------- helpers ----------
__device__ __forceinline__ void lds_load16(const void* g, void* l) {
  __builtin_amdgcn_global_load_lds((const __attribute__((address_space(1))) void*)g,
                                   (__attribute__((address_space(3))) void*)l,
                                   16, 0, 0);
}

// Bijective XCD-chunk swizzle (T1, m204): orig%8 = XCD under round-robin
// dispatch; give each XCD a CONTIGUOUS tile range so blocks sharing A/h rows
// hit the same per-XCD L2. Requires nwg % 8 == 0 (all our grids comply).
__device__ __forceinline__ void xcd_remap(int& bx, int& by) {
  const int nwg = gridDim.x * gridDim.y;
  if ((nwg & 7) == 0) {
    const int orig = blockIdx.x + gridDim.x * blockIdx.y;
    const int id = (orig & 7) * (nwg >> 3) + (orig >> 3);
    bx = id % gridDim.x;
    by = id / gridDim.x;
  } else {
    bx = blockIdx.x;
    by = blockIdx.y;
  }
}

// ---------- diagnostic fill ----------
__global__ __launch_bounds__(256) void fill_const(float* __restrict__ out, float C, int n) {
  int i = blockIdx.x * 256 + threadIdx.x;
  if (i < n) out[i] = C;
}

// ---------- legacy prep: tokens -> x copy + qkv bias concat (fallback flow) ----------
__global__ __launch_bounds__(256) void prep(const float* __restrict__ tokens,
                                            float* __restrict__ x,
                                            const float* __restrict__ bq,
                                            const float* __restrict__ bk,
                                            const float* __restrict__ bv,
                                            float* __restrict__ bqkvc) {
  const int b = blockIdx.x;
  if (b < 8192) {
    int i = b * 256 + threadIdx.x;
    x[i] = tokens[i];
  } else {
    int idx = (b - 8192) * 256 + threadIdx.x;
    if (idx < LL * 1536) {
      int l = idx / 1536, n = idx % 1536;
      float v;
      if (n < 512)       v = bq[l * 512 + n];
      else if (n < 1024) v = bk[l * 512 + n - 512];
      else               v = bv[l * 512 + n - 1024];
      bqkvc[idx] = v;
    }
  }
}

// ---------- weight transpose fp32(K,N)->bf16(N,K); + qkv bias concat blocks ----------
__global__ __launch_bounds__(256) void transpose_all(const float* __restrict__ Wq,
                                                     const float* __restrict__ Wk,
                                                     const float* __restrict__ Wv,
                                                     const float* __restrict__ Wo,
                                                     const float* __restrict__ W1,
                                                     const float* __restrict__ W2,
                                                     __hip_bfloat16* __restrict__ wqkvT,
                                                     __hip_bfloat16* __restrict__ woT,
                                                     __hip_bfloat16* __restrict__ w1T,
                                                     __hip_bfloat16* __restrict__ w2T,
                                                     const float* __restrict__ bq,
                                                     const float* __restrict__ bk,
                                                     const float* __restrict__ bv,
                                                     float* __restrict__ bqkvc) {
  const int l = blockIdx.y;
  const int b = blockIdx.x;
  if (b >= 3072) {
    int n = (b - 3072) * 256 + threadIdx.x;
    if (n < 1536) {
      float v;
      if (n < 512)       v = bq[l * 512 + n];
      else if (n < 1024) v = bk[l * 512 + n - 512];
      else               v = bv[l * 512 + n - 1024];
      bqkvc[l * 1536 + n] = v;
    }
    return;
  }
  __shared__ float tile[32][33];
  const float* src;
  __hip_bfloat16* dst;
  int K, N, t;
  if (b < 768) {
    int which = b >> 8; t = b & 255;
    src = ((which == 0) ? Wq : (which == 1) ? Wk : Wv) + (size_t)l * 262144;
    dst = wqkvT + (size_t)l * 786432 + which * 262144;
    K = 512; N = 512;
  } else if (b < 1024) {
    t = b - 768;  src = Wo + (size_t)l * 262144;  dst = woT + (size_t)l * 262144;  K = 512; N = 512;
  } else if (b < 2048) {
    t = b - 1024; src = W1 + (size_t)l * 1048576; dst = w1T + (size_t)l * 1048576; K = 512; N = 2048;
  } else {
    t = b - 2048; src = W2 + (size_t)l * 1048576; dst = w2T + (size_t)l * 1048576; K = 2048; N = 512;
  }
  const int tilesN = N >> 5;
  const int n0 = (t % tilesN) * 32, k0 = (t / tilesN) * 32;
  const int tx = threadIdx.x & 31, ty = threadIdx.x >> 5;
#pragma unroll
  for (int r = 0; r < 32; r += 8)
    tile[ty + r][tx] = src[(size_t)(k0 + ty + r) * N + n0 + tx];
  __syncthreads();
#pragma unroll
  for (int r = 0; r < 32; r += 8)
    dst[(size_t)(n0 + ty + r) * K + k0 + tx] = __float2bfloat16(tile[tx][ty + r]);
}

// ---------- LayerNorm: fp32 -> bf16 ----------
__global__ __launch_bounds__(256) void ln_kernel(const float* __restrict__ x,
                                                 const float* __restrict__ g,
                                                 const float* __restrict__ b,
                                                 __hip_bfloat16* __restrict__ out) {
  const int wave = threadIdx.x >> 6, lane = threadIdx.x & 63;
  const int row = blockIdx.x * 4 + wave;
  const float* xr = x + (size_t)row * DD;
  float v[8];
  float s = 0.f;
#pragma unroll
  for (int i = 0; i < 8; ++i) { v[i] = xr[lane + i * 64]; s += v[i]; }
#pragma unroll
  for (int off = 32; off; off >>= 1) s += __shfl_xor(s, off);
  float mu = s * (1.f / DD);
  float qs = 0.f;
#pragma unroll
  for (int i = 0; i < 8; ++i) { float d = v[i] - mu; qs += d * d; }
#pragma unroll
  for (int off = 32; off; off >>= 1) qs += __shfl_xor(qs, off);
  float rstd = rsqrtf(qs * (1.f / DD) + 1e-5f);
#pragma unroll
  for (int i = 0; i < 8; ++i) {
    int c = lane + i * 64;
    out[(size_t)row * DD + c] = __float2bfloat16((v[i] - mu) * rstd * g[c] + b[c]);
  }
}

// ---------- final LayerNorm: fp32 -> fp32 ----------
__global__ __launch_bounds__(256) void ln_f32out(const float* __restrict__ x,
                                                 const float* __restrict__ g,
                                                 const float* __restrict__ b,
                                                 float* __restrict__ out) {
  const int wave = threadIdx.x >> 6, lane = threadIdx.x & 63;
  const int row = blockIdx.x * 4 + wave;
  const float* xr = x + (size_t)row * DD;
  float v[8];
  float s = 0.f;
#pragma unroll
  for (int i = 0; i < 8; ++i) { v[i] = xr[lane + i * 64]; s += v[i]; }
#pragma unroll
  for (int off = 32; off; off >>= 1) s += __shfl_xor(s, off);
  float mu = s * (1.f / DD);
  float qs = 0.f;
#pragma unroll
  for (int i = 0; i < 8; ++i) { float d = v[i] - mu; qs += d * d; }
#pragma unroll
  for (int off = 32; off; off >>= 1) qs += __shfl_xor(qs, off);
  float rstd = rsqrtf(qs * (1.f / DD) + 1e-5f);
#pragma unroll
  for (int i = 0; i < 8; ++i) {
    int c = lane + i * 64;
    out[(size_t)row * DD + c] = (v[i] - mu) * rstd * g[c] + b[c];
  }
}

// ---------- MFMA GEMM: double-pumped BK=64, XCD-chunk swizzled ----------
enum { EPI_BF16 = 0, EPI_GELU = 1, EPI_ADDF32 = 2, EPI_RES = 3 };

template <int EPI, bool ROPE, int BM, int BN>
__global__ __launch_bounds__(256, 1) void gemm_bt(const __hip_bfloat16* __restrict__ A,
                                                  const __hip_bfloat16* __restrict__ BT,
                                                  const float* __restrict__ bias,
                                                  __hip_bfloat16* __restrict__ Obf,
                                                  float* __restrict__ Of,
                                                  const float* __restrict__ Orin,
                                                  __hip_bfloat16* __restrict__ VTo,
                                                  int M, int N, int K, int KS,
                                                  int ostride, int ooff) {
  constexpr int MI = (BM == 64) ? 2 : ((BN == 128) ? 4 : 2);
  constexpr int NJ = (BM == 64) ? 2 : 4;
  __shared__ __align__(16) __hip_bfloat16 Ash[2][2][BM * 32];
  __shared__ __align__(16) __hip_bfloat16 Bsh[2][2][BN * 32];
  const int tid = threadIdx.x;
  const int wave = tid >> 6;
  const int lane = tid & 63;
  int bx, by;
  xcd_remap(bx, by);
  const int m0 = by * BM;
  const int n0 = bx * BN;
  const int kbase = blockIdx.z * KS;
  const int wm = (BM == 64) ? ((wave >> 1) * 32)
                            : ((BN == 128) ? ((wave >> 1) * 64) : (wave * 32));
  const int wn = (BM == 64) ? ((wave & 1) * 32)
                            : ((BN == 128) ? ((wave & 1) * 64) : 0);
  const int l15 = lane & 15;
  const int quad = lane >> 4;

  f32x4 acc[MI][NJ] = {};

  const int r0 = tid >> 2;
  const int o0 = (tid & 3) * 8;

  const __hip_bfloat16* Ap0 = A + (size_t)(m0 + r0) * K + kbase + o0;
  const __hip_bfloat16* Ap1 = Ap0 + (size_t)64 * K;
  const __hip_bfloat16* Bp0 = BT + (size_t)(n0 + r0) * K + kbase + o0;
  const __hip_bfloat16* Bp1 = Bp0 + (size_t)64 * K;

  auto stage64 = [&](int buf, int k) {
    lds_load16(Ap0 + k,      &Ash[buf][0][wave * 512]);
    lds_load16(Ap0 + k + 32, &Ash[buf][1][wave * 512]);
    if constexpr (BM == 128) {
      lds_load16(Ap1 + k,      &Ash[buf][0][2048 + wave * 512]);
      lds_load16(Ap1 + k + 32, &Ash[buf][1][2048 + wave * 512]);
    }
    lds_load16(Bp0 + k,      &Bsh[buf][0][wave * 512]);
    lds_load16(Bp0 + k + 32, &Bsh[buf][1][wave * 512]);
    if constexpr (BN == 128) {
      lds_load16(Bp1 + k,      &Bsh[buf][0][2048 + wave * 512]);
      lds_load16(Bp1 + k + 32, &Bsh[buf][1][2048 + wave * 512]);
    }
  };
  auto compute = [&](const __hip_bfloat16* As, const __hip_bfloat16* Bs) {
    bf16x8 af[MI], bfr[NJ];
#pragma unroll
    for (int i = 0; i < MI; ++i)
      af[i] = *(const bf16x8*)&As[(wm + i * 16 + l15) * 32 + quad * 8];
#pragma unroll
    for (int j = 0; j < NJ; ++j)
      bfr[j] = *(const bf16x8*)&Bs[(wn + j * 16 + l15) * 32 + quad * 8];
#pragma unroll
    for (int i = 0; i < MI; ++i)
#pragma unroll
      for (int j = 0; j < NJ; ++j)
        acc[i][j] = __builtin_amdgcn_mfma_f32_16x16x32_bf16(af[i], bfr[j], acc[i][j], 0, 0, 0);
  };
  auto compute64 = [&](int buf) {
    compute(Ash[buf][0], Bsh[buf][0]);
    compute(Ash[buf][1], Bsh[buf][1]);
  };

  stage64(0, 0);
  for (int k0 = 0; k0 < KS; k0 += 128) {       // KS % 128 == 0
    __syncthreads();
    if (k0 + 64 < KS) stage64(1, k0 + 64);
    compute64(0);
    __syncthreads();
    if (k0 + 128 < KS) stage64(0, k0 + 128);
    compute64(1);
  }

  if constexpr (ROPE) {
    if (n0 < 1024) {
      // q/k sections: rotate (d, d+32) pairs; write to qkv row-major
#pragma unroll
      for (int j = 0; j < 2; ++j) {
        const int col = n0 + wn + j * 16 + l15;
        const float bv0 = bias[col], bv1 = bias[col + 32];
        const float freq = __powf(10000.f, -(float)(j * 16 + l15) * (1.f / 32.f));
#pragma unroll
        for (int i = 0; i < MI; ++i) {
          const int row = m0 + wm + i * 16 + quad * 4;
#pragma unroll
          for (int r = 0; r < 4; ++r) {
            const int t = (row + r) & 2047;
            float sn, cs;
            __sincosf((float)t * freq, &sn, &cs);
            const float a0 = acc[i][j][r] + bv0;
            const float a1 = acc[i][j + 2][r] + bv1;
            const size_t idx = (size_t)(row + r) * ostride + ooff + col;
            Obf[idx]      = __float2bfloat16(a0 * cs - a1 * sn);
            Obf[idx + 32] = __float2bfloat16(a1 * cs + a0 * sn);
          }
        }
      }
    } else {
      // V section: bias + store transposed VT[d][token]
#pragma unroll
      for (int j = 0; j < NJ; ++j) {
        const int col = n0 + wn + j * 16 + l15;
        const float bv = bias[col];
        const int d = col - 1024;
#pragma unroll
        for (int i = 0; i < MI; ++i) {
          const int row = m0 + wm + i * 16 + quad * 4;
#pragma unroll
          for (int r = 0; r < 4; ++r)
            VTo[(size_t)d * 4096 + row + r] = __float2bfloat16(acc[i][j][r] + bv);
        }
      }
    }
    return;
  }

#pragma unroll
  for (int j = 0; j < NJ; ++j) {
    const int col = n0 + wn + j * 16 + l15;
    const float bv = (EPI == EPI_RES || blockIdx.z == 0) ? bias[col] : 0.f;
#pragma unroll
    for (int i = 0; i < MI; ++i) {
      const int row = m0 + wm + i * 16 + quad * 4;
#pragma unroll
      for (int r = 0; r < 4; ++r) {
        float v = acc[i][j][r] + bv;
        size_t idx = (size_t)(row + r) * ostride + ooff + col;
        if (EPI == EPI_BF16) {
          Obf[idx] = __float2bfloat16(v);
        } else if (EPI == EPI_GELU) {
          float ge = 0.5f * v * (1.f + erff(v * 0.70710678118654752f));
          Obf[idx] = __float2bfloat16(ge);
        } else if (EPI == EPI_RES) {
          Of[idx] = Orin[idx] + v;               // fused residual, race-free
        } else {
          atomicAdd(&Of[idx], v);                // fallback split-K
        }
      }
    }
  }
}

// ---------- MFMA flash attention; V from transposed VT; NO-MAX softmax ----------
// XCD-chunked: each XCD owns 2 (b,h) K/V planes -> L2-resident reads.
// Ksh LDS staging retained: each K row is reused ~10x per block (reuse count,
// not L2 residency, justifies staging — R9 lesson).
__global__ __launch_bounds__(256, 1) void attn_mfma(const __hip_bfloat16* __restrict__ qkv,
                                                    const __hip_bfloat16* __restrict__ VT,
                                                    __hip_bfloat16* __restrict__ ao) {
  constexpr int KPAD = 72;
  constexpr int PPAD = 40;
  __shared__ __align__(16) __hip_bfloat16 Ksh[320 * KPAD];
  __shared__ __align__(16) __hip_bfloat16 Psh[4 * 16 * PPAD];
  const int tid = threadIdx.x;
  const int wave = tid >> 6;
  const int lane = tid & 63;
  const int l15 = lane & 15;
  const int quad = lane >> 4;
  int bx, by;
  xcd_remap(bx, by);                 // grid (32,16): 512 wg, %8==0
  const int bh = by;
  const int b = bh >> 3, h = bh & 7;
  const int q0 = bx * 64;
  const int j0 = (q0 >= WWIN) ? (q0 - WWIN) : 0;   // 64-aligned
  const int nk = (q0 + 63) - j0 + 1;               // <= 320

  const size_t baseK = ((size_t)(b * TT + j0)) * 1536 + 512 + h * 64;
  for (int c = tid; c < nk * 8; c += 256) {
    int row = c >> 3, cc = (c & 7) * 8;
    *(uint4*)&Ksh[row * KPAD + cc] = *(const uint4*)&qkv[baseK + (size_t)row * 1536 + cc];
  }
  __syncthreads();

  const int qt0 = q0 + wave * 16;
  const size_t baseQ = ((size_t)(b * TT + qt0 + l15)) * 1536 + h * 64;
  const bf16x8 aq0 = *(const bf16x8*)&qkv[baseQ + quad * 8];
  const bf16x8 aq1 = *(const bf16x8*)&qkv[baseQ + 32 + quad * 8];

  const __hip_bfloat16* V0 = VT + (size_t)(h * 64 + l15) * 4096 + (size_t)b * 2048 + j0;

  f32x4 o0 = {}, o1 = {}, o2 = {}, o3 = {};
  float lsum[4] = {0.f, 0.f, 0.f, 0.f};

  const int klo = (qt0 > (WWIN - 1)) ? (qt0 - (WWIN - 1)) : 0;
  const int c_lo = (klo - j0) >> 5;
  const int c_hi = (qt0 + 15 - j0) >> 5;
  __hip_bfloat16* Pw = &Psh[wave * 16 * PPAD];

  for (int c = c_lo; c <= c_hi; ++c) {
    const int krel = c * 32;
    bf16x8 bk00 = *(const bf16x8*)&Ksh[(krel + l15) * KPAD + quad * 8];
    bf16x8 bk01 = *(const bf16x8*)&Ksh[(krel + l15) * KPAD + 32 + quad * 8];
    bf16x8 bk10 = *(const bf16x8*)&Ksh[(krel + 16 + l15) * KPAD + quad * 8];
    bf16x8 bk11 = *(const bf16x8*)&Ksh[(krel + 16 + l15) * KPAD + 32 + quad * 8];
    f32x4 z = {};
    f32x4 s0 = __builtin_amdgcn_mfma_f32_16x16x32_bf16(aq0, bk00, z, 0, 0, 0);
    s0 = __builtin_amdgcn_mfma_f32_16x16x32_bf16(aq1, bk01, s0, 0, 0, 0);
    f32x4 s1 = __builtin_amdgcn_mfma_f32_16x16x32_bf16(aq0, bk10, z, 0, 0, 0);
    s1 = __builtin_amdgcn_mfma_f32_16x16x32_bf16(aq1, bk11, s1, 0, 0, 0);

    const int jj0 = j0 + krel + l15;
    const int jj1 = jj0 + 16;
#pragma unroll
    for (int r = 0; r < 4; ++r) {
      const int qrow = qt0 + quad * 4 + r;
      const bool ok0 = (jj0 <= qrow) && ((qrow - jj0) < WWIN);
      const bool ok1 = (jj1 <= qrow) && ((qrow - jj1) < WWIN);
      const float p0 = ok0 ? __expf(s0[r] * 0.125f) : 0.f;
      const float p1 = ok1 ? __expf(s1[r] * 0.125f) : 0.f;
      lsum[r] += p0 + p1;
      const int qloc = quad * 4 + r;
      Pw[qloc * PPAD + l15]      = __float2bfloat16(p0);
      Pw[qloc * PPAD + 16 + l15] = __float2bfloat16(p1);
    }
    asm volatile("s_waitcnt lgkmcnt(0)" ::: "memory");
    __builtin_amdgcn_wave_barrier();
    const bf16x8 pa = *(const bf16x8*)&Pw[l15 * PPAD + quad * 8];

    const int kgl = krel + quad * 8;
#pragma unroll
    for (int t = 0; t < 4; ++t) {
      const bf16x8 bv = *(const bf16x8*)&V0[(size_t)t * 65536 + kgl];
      if (t == 0)      o0 = __builtin_amdgcn_mfma_f32_16x16x32_bf16(pa, bv, o0, 0, 0, 0);
      else if (t == 1) o1 = __builtin_amdgcn_mfma_f32_16x16x32_bf16(pa, bv, o1, 0, 0, 0);
      else if (t == 2) o2 = __builtin_amdgcn_mfma_f32_16x16x32_bf16(pa, bv, o2, 0, 0, 0);
      else             o3 = __builtin_amdgcn_mfma_f32_16x16x32_bf16(pa, bv, o3, 0, 0, 0);
    }
    __builtin_amdgcn_wave_barrier();
  }

#pragma unroll
  for (int r = 0; r < 4; ++r) {
#pragma unroll
    for (int off = 8; off; off >>= 1) lsum[r] += __shfl_xor(lsum[r], off, 16);
  }

#pragma unroll
  for (int r = 0; r < 4; ++r) {
    const float inv = 1.f / lsum[r];
    const size_t ob = ((size_t)(b * TT + qt0 + quad * 4 + r)) * DD + h * 64 + l15;
    ao[ob]      = __float2bfloat16(o0[r] * inv);
    ao[ob + 16] = __float2bfloat16(o1[r] * inv);
    ao[ob + 32] = __float2bfloat16(o2[r] * inv);
    ao[ob + 48] = __float2bfloat16(o3[r] * inv);
  }
}

// ---------- host launch ----------
extern "C" void kernel_launch(void* const* d_in, const int* in_sizes, int n_in,
                              void* d_out, int out_size, void* d_ws, size_t ws_size,
                              hipStream_t stream) {
  float* outF = (float*)d_out;   // fp32 output; doubles as residual x

  int code = 0;
  if (n_in != 19)                      code = 1;
  else if (in_sizes[0]  != 2097152)    code = 2;
  else if (in_sizes[1]  != 1048576)    code = 3;
  else if (in_sizes[9]  != 4194304)    code = 4;
  else if (in_sizes[17] != 512)        code = 5;
  if (code != 0 || ws_size < 27287552ull) {
    float C = code ? (150.f + 15.f * (float)code) : (1000.f + (float)(ws_size >> 20));
    fill_const<<<8192, 256, 0, stream>>>(outF, C, NOUT);
    return;
  }

  const float* tokens = (const float*)d_in[0];
  const float* Wq  = (const float*)d_in[1];
  const float* Wk  = (const float*)d_in[2];
  const float* Wv  = (const float*)d_in[3];
  const float* Wo  = (const float*)d_in[4];
  const float* bq  = (const float*)d_in[5];
  const float* bk  = (const float*)d_in[6];
  const float* bv  = (const float*)d_in[7];
  const float* bo  = (const float*)d_in[8];
  const float* W1  = (const float*)d_in[9];
  const float* b1  = (const float*)d_in[10];
  const float* W2  = (const float*)d_in[11];
  const float* b2  = (const float*)d_in[12];
  const float* g1  = (const float*)d_in[13];
  const float* be1 = (const float*)d_in[14];
  const float* g2  = (const float*)d_in[15];
  const float* be2 = (const float*)d_in[16];
  const float* gf  = (const float*)d_in[17];
  const float* bf  = (const float*)d_in[18];

  char* ws = (char*)d_ws;
  __hip_bfloat16* xnao  = (__hip_bfloat16*)(ws + 0);          //  4,194,304 (xn/ao aliased)
  __hip_bfloat16* qkv   = (__hip_bfloat16*)(ws + 4194304);    // 12,582,912
  __hip_bfloat16* hbuf  = (__hip_bfloat16*)(ws + 4194304);    // 16,777,216 span
  __hip_bfloat16* VT    = (__hip_bfloat16*)(ws + 16777216);   //  4,194,304 (attn phase only)

  const bool big = ws_size >= 46161920ull;   // hoisted transposed weights fit
  __hip_bfloat16 *wqkvT, *woT, *w1T, *w2T;
  float* bqkvc;
  if (big) {
    wqkvT = (__hip_bfloat16*)(ws + 20971520);
    woT   = (__hip_bfloat16*)(ws + 27262976);
    w1T   = (__hip_bfloat16*)(ws + 29360128);
    w2T   = (__hip_bfloat16*)(ws + 37748736);
    bqkvc = (float*)(ws + 46137344);
  } else {
    wqkvT = (__hip_bfloat16*)(ws + 20971520);
    woT   = (__hip_bfloat16*)(ws + 22544384);
    w1T   = (__hip_bfloat16*)(ws + 23068672);
    w2T   = (__hip_bfloat16*)(ws + 25165824);
    bqkvc = (float*)(ws + 27262976);
  }
  __hip_bfloat16* xn = xnao;
  __hip_bfloat16* ao = xnao;
  float* x = outF;

  if (big) {
    // ---- flow: hoisted transposes (+bias blocks), fused-residual GEMMs ----
    transpose_all<<<dim3(3078, 4), 256, 0, stream>>>(Wq, Wk, Wv, Wo, W1, W2,
                                                     wqkvT, woT, w1T, w2T,
                                                     bq, bk, bv, bqkvc);
    ln_kernel<<<1024, 256, 0, stream>>>(tokens, g1, be1, xn);
    for (int l = 0; l < LL; ++l) {
      __hip_bfloat16* qkvT_l = wqkvT + (size_t)l * 786432;
      __hip_bfloat16* woT_l  = woT   + (size_t)l * 262144;
      __hip_bfloat16* w1T_l  = w1T   + (size_t)l * 1048576;
      __hip_bfloat16* w2T_l  = w2T   + (size_t)l * 1048576;

      gemm_bt<EPI_BF16, true, 128, 64><<<dim3(24, 32), 256, 0, stream>>>(
          xn, qkvT_l, bqkvc + l * 1536, qkv, nullptr, nullptr, VT,
          MM, 1536, 512, 512, 1536, 0);
      attn_mfma<<<dim3(32, 16), 256, 0, stream>>>(qkv, VT, ao);
      // Wo: 64x64 tile, full-K, fused residual (x = xin + ao@WoT + bo)
      gemm_bt<EPI_RES, false, 64, 64><<<dim3(8, 64), 256, 0, stream>>>(
          ao, woT_l, bo + l * 512, nullptr, x, (l == 0) ? tokens : x, nullptr,
          MM, 512, 512, 512, 512, 0);
      ln_kernel<<<1024, 256, 0, stream>>>(x, g2 + l * 512, be2 + l * 512, xn);
      gemm_bt<EPI_GELU, false, 128, 128><<<dim3(16, 32), 256, 0, stream>>>(
          xn, w1T_l, b1 + l * 2048, hbuf, nullptr, nullptr, nullptr,
          MM, 2048, 512, 512, 2048, 0);
      // FFN2: 64x64 tile, full-K=2048, fused residual (x += h@W2T + b2)
      gemm_bt<EPI_RES, false, 64, 64><<<dim3(8, 64), 256, 0, stream>>>(
          hbuf, w2T_l, b2 + l * 512, nullptr, x, x, nullptr,
          MM, 512, 2048, 2048, 512, 0);
      if (l < LL - 1)
        ln_kernel<<<1024, 256, 0, stream>>>(x, g1 + (l + 1) * 512,
                                            be1 + (l + 1) * 512, xn);
      else
        ln_f32out<<<1024, 256, 0, stream>>>(x, gf, bf, outF);  // in-place safe
    }
    return;
  }

  // ---- fallback: per-layer transposes, atomic split-K ----
  prep<<<8216, 256, 0, stream>>>(tokens, x, bq, bk, bv, bqkvc);

  for (int l = 0; l < LL; ++l) {
    transpose_all<<<dim3(3072, 1), 256, 0, stream>>>(
        Wq + (size_t)l * 262144, Wk + (size_t)l * 262144, Wv + (size_t)l * 262144,
        Wo + (size_t)l * 262144, W1 + (size_t)l * 1048576, W2 + (size_t)l * 1048576,
        wqkvT, woT, w1T, w2T, bq, bk, bv, bqkvc);

    ln_kernel<<<1024, 256, 0, stream>>>(x, g1 + l * 512, be1 + l * 512, xn);
    gemm_bt<EPI_BF16, true, 128, 64><<<dim3(24, 32), 256, 0, stream>>>(
        xn, wqkvT, bqkvc + l * 1536, qkv, nullptr, nullptr, VT,
        MM, 1536, 512, 512, 1536, 0);
    attn_mfma<<<dim3(32, 16), 256, 0, stream>>>(qkv, VT, ao);
    gemm_bt<EPI_ADDF32, false, 128, 64><<<dim3(8, 32, 2), 256, 0, stream>>>(
        ao, woT, bo + l * 512, nullptr, x, nullptr, nullptr,
        MM, 512, 512, 256, 512, 0);
    ln_kernel<<<1024, 256, 0, stream>>>(x, g2 + l * 512, be2 + l * 512, xn);
    gemm_bt<EPI_GELU, false, 128, 128><<<dim3(16, 32), 256, 0, stream>>>(
        xn, w1T, b1 + l * 2048, hbuf, nullptr, nullptr, nullptr,
        MM, 2048, 512, 512, 2048, 0);
    gemm_bt<EPI_ADDF32, false, 128, 128><<<dim3(4, 32, 4), 256, 0, stream>>>(
        hbuf, w2T, b2 + l * 512, nullptr, x, nullptr, nullptr,
        MM, 512, 2048, 512, 512, 0);
  }
  ln_f32out<<<1024, 256, 0, stream>>>(x, gf, bf, outF);
}